// Round 11
// baseline (239.330 us; speedup 1.0000x reference)
//
#include <hip/hip_runtime.h>

#define NN 4096
#define NE 32768
#define PED 16
#define HID 128
#define CW 16          // columns per block slice
#define NCHUNK 64      // NN/64 rows per chunk
#define THREADS 1024   // 16 waves
#define PASSES 4       // NCHUNK / 16 waves

typedef _Float16 h_t;
typedef _Float16 h8 __attribute__((ext_vector_type(8)));
typedef unsigned long long u64;

// LDS BYTE offset for SORTED slot p (row rowperm[p]).
// 128-B window = 4 slots x 32 B (lo half 16 B + hi half 16 B = 16 fp16 cols).
// granule g = ((p&3)<<1) | window-parity; hi half = ^16.
__device__ __forceinline__ int xp(int p) {
  int g = ((p & 3) << 1) | ((p >> 2) & 1);
  return ((p >> 2) << 7) | (g << 4);
}

// ---- ALL preprocessing in one single-block kernel ----
// phases (LDS-separated by __syncthreads):
//  A: degree counting via LDS atomics (no global memset needed)
//  B: dinv, clamp, histogram -> counting sort -> chunk geometry
//  C: fill lane-major ELL (fill order) to global esrc
//  D: greedy bipartite edge-coloring per 8-lane track -> edst (+ tail zero)
__global__ __launch_bounds__(1024)
void prep_all(const int* __restrict__ senders, const int* __restrict__ receivers,
              int* __restrict__ rowperm_g, int* __restrict__ chunk_off_g,
              int* __restrict__ chunk_len_g,
              int2* __restrict__ esrc, int2* __restrict__ edst) {
  __shared__ int ld_out[NN];     // 16 KB: out-degrees
  __shared__ int ld_d[NN];       // 16 KB: in-degrees (clamped in phase B)
  __shared__ int sortpos_l[NN];  // 16 KB
  __shared__ int rowperm_l[NN];  // 16 KB
  __shared__ float dinv_l[NN];   // 16 KB
  __shared__ int fillc_l[NN];    // 16 KB
  __shared__ int hist[64];
  __shared__ int hbase[64];
  __shared__ int coff[NCHUNK + 1];
  __shared__ int clen[NCHUNK];
  int t = threadIdx.x;

  for (int i = t; i < NN; i += 1024) { ld_out[i] = 0; ld_d[i] = 0; fillc_l[i] = 0; }
  if (t < 64) hist[t] = 0;
  __syncthreads();
  // A: count
  for (int e = t; e < NE; e += 1024) {
    atomicAdd(&ld_out[senders[e]], 1);
    atomicAdd(&ld_d[receivers[e]], 1);
  }
  __syncthreads();
  // B: row-level
  for (int r = t; r < NN; r += 1024) {
    int od = ld_out[r]; if (od < 1) od = 1;
    dinv_l[r] = 1.0f / (float)od;
    int d = ld_d[r]; if (d > 63) d = 63;
    ld_d[r] = d;                 // each r owned by one thread; read+write same thread
    atomicAdd(&hist[d], 1);
  }
  __syncthreads();
  if (t == 0) { int acc = 0; for (int i = 0; i < 64; ++i) { hbase[i] = acc; acc += hist[i]; } }
  __syncthreads();
  for (int r = t; r < NN; r += 1024) {
    int pos = atomicAdd(&hbase[ld_d[r]], 1);
    rowperm_l[pos] = r;
    sortpos_l[r] = pos;
  }
  __syncthreads();
  if (t < NCHUNK) {
    int m = 0;
    for (int i = 0; i < 64; ++i) { int d = ld_d[rowperm_l[(t << 6) + i]]; if (d > m) m = d; }
    clen[t] = (m + 1) & ~1;  // even
  }
  __syncthreads();
  if (t == 0) {
    int acc = 0;
    for (int c = 0; c < NCHUNK; ++c) { coff[c] = acc; acc += clen[c] << 6; }
    coff[NCHUNK] = acc;
  }
  __syncthreads();
  // write row-level outputs consumed by fused_kernel
  for (int i = t; i < NN; i += 1024) rowperm_g[i] = rowperm_l[i];
  if (t < NCHUNK) chunk_len_g[t] = clen[t];
  if (t <= NCHUNK) chunk_off_g[t] = coff[t];
  // C: fill (scattered global writes; all lookups in LDS)
  for (int e = t; e < NE; e += 1024) {
    int r = receivers[e], s = senders[e];
    int p = sortpos_l[r];
    int tslot = atomicAdd(&fillc_l[r], 1);
    int slot = coff[p >> 6] + (tslot << 6) + (p & 63);
    esrc[slot] = make_int2(xp(sortpos_l[s]), __float_as_int(dinv_l[s]));
  }
  __threadfence();
  __syncthreads();   // esrc complete & visible (same CU, L2-hot)
  // D: tail zero + coloring (threads 0..511, one per 8-lane track)
  int total = coff[NCHUNK];
  for (int i = t; i < 2048; i += 1024) edst[total + i] = make_int2(0, 0);
  if (t < NCHUNK * 8) {
    int c = t >> 3;
    int trk = t & 7;
    int base = coff[c];
    int len = clen[c];
    int l0 = trk << 3;
    int d[8];
    u64 freeL[8];
    int dmax = 0;
#pragma unroll
    for (int j = 0; j < 8; ++j) {
      int dd = ld_d[rowperm_l[(c << 6) + l0 + j]];  // clamped <= 63
      d[j] = dd;
      if (dd > dmax) dmax = dd;
    }
    if (len > 63) {  // fallback (never hit for Poisson(8) degrees): plain copy
#pragma unroll
      for (int j = 0; j < 8; ++j) {
        for (int tt = 0; tt < d[j]; ++tt) edst[base + (tt << 6) + l0 + j] = esrc[base + (tt << 6) + l0 + j];
        for (int tt = d[j]; tt < len; ++tt) edst[base + (tt << 6) + l0 + j] = make_int2(((tt + j) & 7) << 4, 0);
      }
      return;
    }
    u64 full = (len == 0) ? 0 : ((1ull << len) - 1);
#pragma unroll
    for (int j = 0; j < 8; ++j) freeL[j] = full;
    u64 fC[8];
#pragma unroll
    for (int q = 0; q < 8; ++q) fC[q] = full;
    for (int tt = 0; tt < dmax; ++tt) {
      int2 cur[8];
#pragma unroll
      for (int j = 0; j < 8; ++j) cur[j] = esrc[base + (tt << 6) + l0 + j];  // L2-hot
#pragma unroll
      for (int j = 0; j < 8; ++j) {
        if (tt < d[j]) {
          int2 e = cur[j];
          int cls = (e.x >> 4) & 7;
          u64 fc = 0;
#pragma unroll
          for (int q = 0; q < 8; ++q) fc = (q == cls) ? fC[q] : fc;
          u64 avail = freeL[j] & fc;
          u64 pool = avail ? avail : freeL[j];   // freeL[j] nonzero: d[j] <= len
          u64 pick = pool & (~pool + 1);
          int slab = __builtin_ctzll(pick);
          freeL[j] &= ~pick;
          if (avail) {
#pragma unroll
            for (int q = 0; q < 8; ++q) if (q == cls) fC[q] &= ~pick;
          }
          edst[base + (slab << 6) + l0 + j] = e;
        }
      }
    }
    // padding: every leftover (lane, slab) gets a class still free at that slab
#pragma unroll
    for (int j = 0; j < 8; ++j) {
      u64 rem = freeL[j];
      while (rem) {
        u64 pick = rem & (~rem + 1);
        rem &= rem - 1;
        int slab = __builtin_ctzll(pick);
        int cls = 0;
#pragma unroll
        for (int q = 7; q >= 0; --q) if (fC[q] & pick) cls = q;
#pragma unroll
        for (int q = 0; q < 8; ++q) if (q == cls) fC[q] &= ~pick;
        edst[base + (slab << 6) + l0 + j] = make_int2(cls << 4, 0);
      }
    }
  }
}

// ---- fused 16-step iteration + output projection epilogue ----

#define MIXL(acc, srcv) \
  asm("v_fma_mix_f32 %0, %1, %2, %0 op_sel_hi:[1,0,0]" : "+v"(acc) : "v"(srcv), "v"(w))
#define MIXH(acc, srcv) \
  asm("v_fma_mix_f32 %0, %1, %2, %0 op_sel:[1,0,0] op_sel_hi:[1,0,0]" : "+v"(acc) : "v"(srcv), "v"(w))

#define MIX16(lo, hi) \
  MIXL(a[0], lo.x);  MIXH(a[1], lo.x);  \
  MIXL(a[2], lo.y);  MIXH(a[3], lo.y);  \
  MIXL(a[4], lo.z);  MIXH(a[5], lo.z);  \
  MIXL(a[6], lo.w);  MIXH(a[7], lo.w);  \
  MIXL(a[8], hi.x);  MIXH(a[9], hi.x);  \
  MIXL(a[10], hi.y); MIXH(a[11], hi.y); \
  MIXL(a[12], hi.z); MIXH(a[13], hi.z); \
  MIXL(a[14], hi.w); MIXH(a[15], hi.w)

__global__ __launch_bounds__(THREADS, 4)
void fused_kernel(const int2* __restrict__ ell,
                  const int* __restrict__ chunk_off,
                  const int* __restrict__ chunk_len,
                  const int* __restrict__ rowperm,
                  const float* __restrict__ W,
                  const float* __restrict__ bvec,
                  float* __restrict__ out) {
  __shared__ __align__(16) h_t X[NN * CW];  // 128 KiB
  __shared__ float pe_lds[CW * PED];        // this block's 16 pe rows
  char* Xb = (char*)X;
  int c0 = blockIdx.x * CW;
  int tid = threadIdx.x;
  int wave = tid >> 6, lane = tid & 63;

  // hoist per-pass invariants (reloaded every step otherwise: __syncthreads
  // fence semantics force the compiler to re-read globals inside the k-loop)
  int baseB[PASSES], lenB[PASSES], djB[PASSES], xbW[PASSES];
#pragma unroll
  for (int pass = 0; pass < PASSES; ++pass) {
    // boustrophedon: each wave's 4 chunk ranks sum to a constant -> balanced
    int chunk = (pass << 4) + ((pass & 1) ? (15 - wave) : wave);
    baseB[pass] = chunk_off[chunk];
    lenB[pass] = chunk_len[chunk];   // even
    djB[pass] = rowperm[(chunk << 6) + lane] - c0;
    xbW[pass] = xp((chunk << 6) + lane);
  }

  // identity slice init (slot p holds row rowperm[p])
  for (int p = tid; p < NN; p += THREADS) {
    int dd = rowperm[p] - c0;
    h8 lo8, hi8;
#pragma unroll
    for (int j = 0; j < 8; ++j) {
      lo8[j] = (h_t)((dd == j) ? 1.0f : 0.0f);
      hi8[j] = (h_t)((dd == 8 + j) ? 1.0f : 0.0f);
    }
    int xb = xp(p);
    *reinterpret_cast<h8*>(Xb + xb) = lo8;
    *reinterpret_cast<h8*>(Xb + (xb ^ 16)) = hi8;
  }
  __syncthreads();

  for (int k = 0; k < PED; ++k) {
    h8 rlo[PASSES], rhi[PASSES];
#pragma unroll
    for (int pass = 0; pass < PASSES; ++pass) {
      int base = baseB[pass];
      int len = lenB[pass];
      float a[16];
#pragma unroll
      for (int j = 0; j < 16; ++j) a[j] = 0.f;
      const int2* ep = ell + base + lane;
      int2 e0 = ep[0];   // padding/slack entries always safe to read & apply
      int2 e1 = ep[64];
      int2 e2 = ep[128];
      int2 e3 = ep[192];
      int4 lo0 = *reinterpret_cast<const int4*>(Xb + e0.x);
      int4 hi0 = *reinterpret_cast<const int4*>(Xb + (e0.x ^ 16));
      for (int t = 0; t < len; t += 2) {    // unroll-2, 4-6-slab ELL prefetch
        int2 e4 = ep[256], e5 = ep[320];
        ep += 128;
        int4 lo1 = *reinterpret_cast<const int4*>(Xb + e1.x);
        int4 hi1 = *reinterpret_cast<const int4*>(Xb + (e1.x ^ 16));
        float w = __int_as_float(e0.y);
        MIX16(lo0, hi0);
        int4 nlo = *reinterpret_cast<const int4*>(Xb + e2.x);
        int4 nhi = *reinterpret_cast<const int4*>(Xb + (e2.x ^ 16));
        w = __int_as_float(e1.y);
        MIX16(lo1, hi1);
        e0 = e2; e1 = e3; e2 = e4; e3 = e5;
        lo0 = nlo; hi0 = nhi;
      }
      h8 plo, phi;
#pragma unroll
      for (int j = 0; j < 8; ++j) { plo[j] = (h_t)a[j]; phi[j] = (h_t)a[8 + j]; }
      rlo[pass] = plo; rhi[pass] = phi;
      int dj = djB[pass];
      if (dj >= 0 && dj < CW) {            // rare: diagonal entry, fp32 pre-rounding
        float dv = a[0];
#pragma unroll
        for (int j = 1; j < 16; ++j) dv = (dj == j) ? a[j] : dv;
        pe_lds[dj * PED + k] = dv;
      }
    }
    if (k != PED - 1) {                    // no write-back needed after last step
      __syncthreads();
#pragma unroll
      for (int pass = 0; pass < PASSES; ++pass) {
        int xb = xbW[pass];                 // balanced write granules
        *reinterpret_cast<h8*>(Xb + xb) = rlo[pass];
        *reinterpret_cast<h8*>(Xb + (xb ^ 16)) = rhi[pass];
      }
      __syncthreads();
    }
  }
  __syncthreads();  // pe_lds visibility

  // epilogue: out[c0+row, h] = sum_k pe_lds[row][k] * W[k][h] + b[h]
  {
    int h = tid & 127;
    int r0 = tid >> 7;   // 0..7, handles rows r0 and r0+8
    float wcol[PED];
#pragma unroll
    for (int kk = 0; kk < PED; ++kk) wcol[kk] = W[kk * HID + h];
    float bb = bvec[h];
#pragma unroll
    for (int half = 0; half < 2; ++half) {
      int row = r0 + (half << 3);
      float acc = bb;
#pragma unroll
      for (int kk = 0; kk < PED; ++kk) acc = fmaf(pe_lds[row * PED + kk], wcol[kk], acc);
      out[(size_t)(c0 + row) * HID + h] = acc;
    }
  }
}

extern "C" void kernel_launch(void* const* d_in, const int* in_sizes, int n_in,
                              void* d_out, int out_size, void* d_ws, size_t ws_size,
                              hipStream_t stream) {
  // inputs: 0=nodes (unused), 1=senders, 2=receivers, 3=W, 4=b
  const int* senders = (const int*)d_in[1];
  const int* receivers = (const int*)d_in[2];
  const float* W = (const float*)d_in[3];
  const float* bvec = (const float*)d_in[4];
  float* out = (float*)d_out;

  char* p = (char*)d_ws;
  int* rowperm = (int*)p;   p += (size_t)NN * 4;
  int* chunk_off = (int*)p; p += 128 * 4;
  int* chunk_len = (int*)p; p += 128 * 4;
  size_t ell_slots = (size_t)64 * NE + 2048;  // worst-case padded bound + tail
  int2* ell = (int2*)p;     p += ell_slots * sizeof(int2);
  int2* ell2 = (int2*)p;

  prep_all<<<1, 1024, 0, stream>>>(senders, receivers, rowperm, chunk_off, chunk_len, ell, ell2);
  fused_kernel<<<NN / CW, THREADS, 0, stream>>>(ell2, chunk_off, chunk_len, rowperm, W, bvec, out);
}

// Round 12
// 227.271 us; speedup vs baseline: 1.0531x; 1.0531x over previous
//
#include <hip/hip_runtime.h>

#define NN 4096
#define NE 32768
#define PED 16
#define HID 128
#define CW 16          // columns per block slice
#define NCHUNK 64      // NN/64 rows per chunk
#define THREADS 1024   // 16 waves
#define PASSES 4       // NCHUNK / 16 waves

typedef _Float16 h_t;
typedef _Float16 h8 __attribute__((ext_vector_type(8)));
typedef unsigned long long u64;

// LDS BYTE offset for SORTED slot p (row rowperm[p]).
// 128-B window = 4 slots x 32 B (lo half 16 B + hi half 16 B = 16 fp16 cols).
// granule g = ((p&3)<<1) | window-parity; hi half = ^16.
__device__ __forceinline__ int xp(int p) {
  int g = ((p & 3) << 1) | ((p >> 2) & 1);
  return ((p >> 2) << 7) | (g << 4);
}

// ---- prep 1: row-level work, one block (inherently serial parts) ----
__global__ __launch_bounds__(1024)
void perm_all(const int* __restrict__ senders, const int* __restrict__ receivers,
              float* __restrict__ dinv_g, int* __restrict__ sortpos_g,
              int* __restrict__ rowperm_g,
              int* __restrict__ chunk_off_g, int* __restrict__ chunk_len_g) {
  __shared__ int ld_out[NN];  // 16 KB out-degrees
  __shared__ int ld_in[NN];   // 16 KB in-degrees (clamped in place)
  __shared__ int rp[NN];      // 16 KB rowperm
  __shared__ int hist[64];
  __shared__ int hbase[64];
  __shared__ int clen[NCHUNK];
  int t = threadIdx.x;
  for (int i = t; i < NN; i += 1024) { ld_out[i] = 0; ld_in[i] = 0; }
  if (t < 64) hist[t] = 0;
  __syncthreads();
  for (int e = t; e < NE; e += 1024) {
    atomicAdd(&ld_out[senders[e]], 1);
    atomicAdd(&ld_in[receivers[e]], 1);
  }
  __syncthreads();
  for (int r = t; r < NN; r += 1024) {
    int od = ld_out[r]; if (od < 1) od = 1;
    dinv_g[r] = 1.0f / (float)od;
    int d = ld_in[r]; if (d > 63) d = 63;
    ld_in[r] = d;  // each r owned by one thread
    atomicAdd(&hist[d], 1);
  }
  __syncthreads();
  if (t == 0) { int acc = 0; for (int i = 0; i < 64; ++i) { hbase[i] = acc; acc += hist[i]; } }
  __syncthreads();
  for (int r = t; r < NN; r += 1024) {
    int pos = atomicAdd(&hbase[ld_in[r]], 1);
    rp[pos] = r;
    sortpos_g[r] = pos;
  }
  __syncthreads();
  for (int i = t; i < NN; i += 1024) rowperm_g[i] = rp[i];
  if (t < NCHUNK) {
    int m = 0;
    for (int i = 0; i < 64; ++i) { int d = ld_in[rp[(t << 6) + i]]; if (d > m) m = d; }
    clen[t] = (m + 1) & ~1;  // even, >= max clamped degree in chunk
    chunk_len_g[t] = clen[t];
  }
  __syncthreads();
  if (t == 0) {
    int acc = 0;
    for (int c = 0; c < NCHUNK; ++c) { chunk_off_g[c] = acc; acc += clen[c] << 6; }
    chunk_off_g[NCHUNK] = acc;
  }
}

// ---- prep 2: per-chunk ELL build + edge-coloring, all in LDS ----
// block c: scan edge list, collect edges whose receiver sorts into chunk c
// into LDS ELL (fill order), greedy-color per 8-lane track (LDS-resident, no
// L2 latency), write final ELL coalesced. Block 0 also zeroes prefetch tail.
__global__ void build_ell(const int* __restrict__ senders, const int* __restrict__ receivers,
                          const int* __restrict__ sortpos, const float* __restrict__ dinv,
                          const int* __restrict__ chunk_off, const int* __restrict__ chunk_len,
                          int2* __restrict__ edst) {
  __shared__ int2 ellA[64 * 64];  // 32 KB incoming (fill order)
  __shared__ int2 ellB[64 * 64];  // 32 KB colored
  __shared__ int fillc[64];
  int c = blockIdx.x;
  int tid = threadIdx.x;  // 512
  int base = chunk_off[c];
  int len = chunk_len[c];
  if (tid < 64) fillc[tid] = 0;
  __syncthreads();
  // scan & fill (receivers read coalesced; sortpos 16 KB -> L1-resident)
  for (int e = tid; e < NE; e += 512) {
    int r = receivers[e];
    int p = sortpos[r];
    if ((p >> 6) == c) {
      int s = senders[e];
      int l = p & 63;
      int ts = atomicAdd(&fillc[l], 1);
      if (ts < 64) ellA[(ts << 6) + l] = make_int2(xp(sortpos[s]), __float_as_int(dinv[s]));
    }
  }
  __syncthreads();
  // greedy bipartite edge-coloring: 8 threads, one per 8-lane track
  if (tid < 8) {
    int l0 = tid << 3;
    int d[8];
    u64 freeL[8];
    int dmax = 0;
#pragma unroll
    for (int j = 0; j < 8; ++j) {
      int dd = fillc[l0 + j]; if (dd > 63) dd = 63;  // d <= len by construction
      d[j] = dd;
      if (dd > dmax) dmax = dd;
    }
    u64 full = (len >= 64) ? ~0ull : ((len == 0) ? 0 : ((1ull << len) - 1));
    u64 fC[8];
#pragma unroll
    for (int j = 0; j < 8; ++j) freeL[j] = full;
#pragma unroll
    for (int q = 0; q < 8; ++q) fC[q] = full;
    for (int tt = 0; tt < dmax; ++tt) {
#pragma unroll
      for (int j = 0; j < 8; ++j) {
        if (tt < d[j]) {
          int2 e = ellA[(tt << 6) + l0 + j];
          int cls = (e.x >> 4) & 7;
          u64 fc = 0;
#pragma unroll
          for (int q = 0; q < 8; ++q) fc = (q == cls) ? fC[q] : fc;
          u64 avail = freeL[j] & fc;
          u64 pool = avail ? avail : freeL[j];   // nonzero: d[j] <= len
          u64 pick = pool & (~pool + 1);
          int slab = __builtin_ctzll(pick);
          freeL[j] &= ~pick;
          if (avail) {
#pragma unroll
            for (int q = 0; q < 8; ++q) if (q == cls) fC[q] &= ~pick;
          }
          ellB[(slab << 6) + l0 + j] = e;
        }
      }
    }
    // padding: every leftover (lane, slab) gets a class still free at that slab
#pragma unroll
    for (int j = 0; j < 8; ++j) {
      u64 rem = freeL[j];
      while (rem) {
        u64 pick = rem & (~rem + 1);
        rem &= rem - 1;
        int slab = __builtin_ctzll(pick);
        int cls = 0;
#pragma unroll
        for (int q = 7; q >= 0; --q) if (fC[q] & pick) cls = q;
#pragma unroll
        for (int q = 0; q < 8; ++q) if (q == cls) fC[q] &= ~pick;
        ellB[(slab << 6) + l0 + j] = make_int2(cls << 4, 0);
      }
    }
  }
  __syncthreads();
  // coalesced write-out
  int n = len << 6;
  for (int i = tid; i < n; i += 512) edst[base + i] = ellB[i];
  if (c == 0) {  // zero prefetch tail (region beyond all chunks)
    int total = chunk_off[NCHUNK];
    for (int i = tid; i < 2048; i += 512) edst[total + i] = make_int2(0, 0);
  }
}

// ---- fused 16-step iteration + output projection epilogue ----

#define MIXL(acc, srcv) \
  asm("v_fma_mix_f32 %0, %1, %2, %0 op_sel_hi:[1,0,0]" : "+v"(acc) : "v"(srcv), "v"(w))
#define MIXH(acc, srcv) \
  asm("v_fma_mix_f32 %0, %1, %2, %0 op_sel:[1,0,0] op_sel_hi:[1,0,0]" : "+v"(acc) : "v"(srcv), "v"(w))

#define MIX16(lo, hi) \
  MIXL(a[0], lo.x);  MIXH(a[1], lo.x);  \
  MIXL(a[2], lo.y);  MIXH(a[3], lo.y);  \
  MIXL(a[4], lo.z);  MIXH(a[5], lo.z);  \
  MIXL(a[6], lo.w);  MIXH(a[7], lo.w);  \
  MIXL(a[8], hi.x);  MIXH(a[9], hi.x);  \
  MIXL(a[10], hi.y); MIXH(a[11], hi.y); \
  MIXL(a[12], hi.z); MIXH(a[13], hi.z); \
  MIXL(a[14], hi.w); MIXH(a[15], hi.w)

__global__ __launch_bounds__(THREADS, 4)
void fused_kernel(const int2* __restrict__ ell,
                  const int* __restrict__ chunk_off,
                  const int* __restrict__ chunk_len,
                  const int* __restrict__ rowperm,
                  const float* __restrict__ W,
                  const float* __restrict__ bvec,
                  float* __restrict__ out) {
  __shared__ __align__(16) h_t X[NN * CW];  // 128 KiB
  __shared__ float pe_lds[CW * PED];        // this block's 16 pe rows
  char* Xb = (char*)X;
  int c0 = blockIdx.x * CW;
  int tid = threadIdx.x;
  int wave = tid >> 6, lane = tid & 63;

  // hoist per-pass invariants (reloaded every step otherwise: __syncthreads
  // fence semantics force the compiler to re-read globals inside the k-loop)
  int baseB[PASSES], lenB[PASSES], djB[PASSES], xbW[PASSES];
#pragma unroll
  for (int pass = 0; pass < PASSES; ++pass) {
    // boustrophedon: each wave's 4 chunk ranks sum to a constant -> balanced
    int chunk = (pass << 4) + ((pass & 1) ? (15 - wave) : wave);
    baseB[pass] = chunk_off[chunk];
    lenB[pass] = chunk_len[chunk];   // even
    djB[pass] = rowperm[(chunk << 6) + lane] - c0;
    xbW[pass] = xp((chunk << 6) + lane);
  }

  // identity slice init (slot p holds row rowperm[p])
  for (int p = tid; p < NN; p += THREADS) {
    int dd = rowperm[p] - c0;
    h8 lo8, hi8;
#pragma unroll
    for (int j = 0; j < 8; ++j) {
      lo8[j] = (h_t)((dd == j) ? 1.0f : 0.0f);
      hi8[j] = (h_t)((dd == 8 + j) ? 1.0f : 0.0f);
    }
    int xb = xp(p);
    *reinterpret_cast<h8*>(Xb + xb) = lo8;
    *reinterpret_cast<h8*>(Xb + (xb ^ 16)) = hi8;
  }
  __syncthreads();

  for (int k = 0; k < PED; ++k) {
    h8 rlo[PASSES], rhi[PASSES];
#pragma unroll
    for (int pass = 0; pass < PASSES; ++pass) {
      int base = baseB[pass];
      int len = lenB[pass];
      float a[16];
#pragma unroll
      for (int j = 0; j < 16; ++j) a[j] = 0.f;
      const int2* ep = ell + base + lane;
      int2 e0 = ep[0];   // padding/slack entries always safe to read & apply
      int2 e1 = ep[64];
      int2 e2 = ep[128];
      int2 e3 = ep[192];
      int4 lo0 = *reinterpret_cast<const int4*>(Xb + e0.x);
      int4 hi0 = *reinterpret_cast<const int4*>(Xb + (e0.x ^ 16));
      for (int t = 0; t < len; t += 2) {    // unroll-2, 4-6-slab ELL prefetch
        int2 e4 = ep[256], e5 = ep[320];
        ep += 128;
        int4 lo1 = *reinterpret_cast<const int4*>(Xb + e1.x);
        int4 hi1 = *reinterpret_cast<const int4*>(Xb + (e1.x ^ 16));
        float w = __int_as_float(e0.y);
        MIX16(lo0, hi0);
        int4 nlo = *reinterpret_cast<const int4*>(Xb + e2.x);
        int4 nhi = *reinterpret_cast<const int4*>(Xb + (e2.x ^ 16));
        w = __int_as_float(e1.y);
        MIX16(lo1, hi1);
        e0 = e2; e1 = e3; e2 = e4; e3 = e5;
        lo0 = nlo; hi0 = nhi;
      }
      h8 plo, phi;
#pragma unroll
      for (int j = 0; j < 8; ++j) { plo[j] = (h_t)a[j]; phi[j] = (h_t)a[8 + j]; }
      rlo[pass] = plo; rhi[pass] = phi;
      int dj = djB[pass];
      if (dj >= 0 && dj < CW) {            // rare: diagonal entry, fp32 pre-rounding
        float dv = a[0];
#pragma unroll
        for (int j = 1; j < 16; ++j) dv = (dj == j) ? a[j] : dv;
        pe_lds[dj * PED + k] = dv;
      }
    }
    if (k != PED - 1) {                    // no write-back needed after last step
      __syncthreads();
#pragma unroll
      for (int pass = 0; pass < PASSES; ++pass) {
        int xb = xbW[pass];                 // balanced write granules
        *reinterpret_cast<h8*>(Xb + xb) = rlo[pass];
        *reinterpret_cast<h8*>(Xb + (xb ^ 16)) = rhi[pass];
      }
      __syncthreads();
    }
  }
  __syncthreads();  // pe_lds visibility

  // epilogue: out[c0+row, h] = sum_k pe_lds[row][k] * W[k][h] + b[h]
  {
    int h = tid & 127;
    int r0 = tid >> 7;   // 0..7, handles rows r0 and r0+8
    float wcol[PED];
#pragma unroll
    for (int kk = 0; kk < PED; ++kk) wcol[kk] = W[kk * HID + h];
    float bb = bvec[h];
#pragma unroll
    for (int half = 0; half < 2; ++half) {
      int row = r0 + (half << 3);
      float acc = bb;
#pragma unroll
      for (int kk = 0; kk < PED; ++kk) acc = fmaf(pe_lds[row * PED + kk], wcol[kk], acc);
      out[(size_t)(c0 + row) * HID + h] = acc;
    }
  }
}

extern "C" void kernel_launch(void* const* d_in, const int* in_sizes, int n_in,
                              void* d_out, int out_size, void* d_ws, size_t ws_size,
                              hipStream_t stream) {
  // inputs: 0=nodes (unused), 1=senders, 2=receivers, 3=W, 4=b
  const int* senders = (const int*)d_in[1];
  const int* receivers = (const int*)d_in[2];
  const float* W = (const float*)d_in[3];
  const float* bvec = (const float*)d_in[4];
  float* out = (float*)d_out;

  char* p = (char*)d_ws;
  int* rowperm = (int*)p;   p += (size_t)NN * 4;
  int* sortpos = (int*)p;   p += (size_t)NN * 4;
  float* dinv = (float*)p;  p += (size_t)NN * 4;
  int* chunk_off = (int*)p; p += 128 * 4;
  int* chunk_len = (int*)p; p += 128 * 4;
  int2* ell2 = (int2*)p;    // <= 64*64*64*8 B + tail, fits workspace

  perm_all<<<1, 1024, 0, stream>>>(senders, receivers, dinv, sortpos, rowperm,
                                   chunk_off, chunk_len);
  build_ell<<<NCHUNK, 512, 0, stream>>>(senders, receivers, sortpos, dinv,
                                        chunk_off, chunk_len, ell2);
  fused_kernel<<<NN / CW, THREADS, 0, stream>>>(ell2, chunk_off, chunk_len, rowperm, W, bvec, out);
}